// Round 7
// baseline (634.597 us; speedup 1.0000x reference)
//
#include <hip/hip_runtime.h>
#include <math.h>

#define N_NODES 100000
#define N_EDGES 1600000
#define IN_F    128
#define NH1     8
#define HID     8
#define C1      64   // NH1*HID
#define C2      40   // N_CLASSES
#define SCAN_B  256
#define N_SBLK  ((N_NODES + SCAN_B - 1) / SCAN_B)   // 391

typedef unsigned short ushort_t;
typedef unsigned int uint_t;
typedef _Float16 half_t;

__device__ __forceinline__ float lrelu(float x) { return x > 0.f ? x : 0.2f * x; }
__device__ __forceinline__ ushort_t f2bf(float f) {
    uint_t u = __float_as_uint(f);
    u = (u + 0x7FFFu + ((u >> 16) & 1u)) >> 16;   // round-to-nearest-even
    return (ushort_t)u;
}
__device__ __forceinline__ float bf2f(ushort_t s) {
    return __uint_as_float(((uint_t)s) << 16);
}

// ---- K1: H1(bf16) = x@W1 ; s1[n,h], d1[n,h] attention dots. 4 nodes/block ----
__global__ __launch_bounds__(256) void k_gemm1(
    const float* __restrict__ x, const float* __restrict__ W1,
    const float* __restrict__ as1, const float* __restrict__ ad1,
    ushort_t* __restrict__ H1, float* __restrict__ s1, float* __restrict__ d1)
{
    __shared__ float xs[4][IN_F];
    int wv = threadIdx.x >> 6, lane = threadIdx.x & 63;
    int n = blockIdx.x * 4 + wv;
    ((float2*)xs[wv])[lane] = ((const float2*)(x + (size_t)n * IN_F))[lane];
    __syncthreads();
    float acc = 0.f;
    #pragma unroll
    for (int k = 0; k < IN_F; k += 4) {
        float4 xk = *(const float4*)&xs[wv][k];
        acc = fmaf(xk.x, W1[(k + 0) * C1 + lane], acc);
        acc = fmaf(xk.y, W1[(k + 1) * C1 + lane], acc);
        acc = fmaf(xk.z, W1[(k + 2) * C1 + lane], acc);
        acc = fmaf(xk.w, W1[(k + 3) * C1 + lane], acc);
    }
    H1[(size_t)n * C1 + lane] = f2bf(acc);
    float ps = acc * as1[lane], pd = acc * ad1[lane];  // lane == h*8+f
    #pragma unroll
    for (int off = 4; off; off >>= 1) {
        ps += __shfl_xor(ps, off);
        pd += __shfl_xor(pd, off);
    }
    if ((lane & 7) == 0) {
        s1[n * NH1 + (lane >> 3)] = ps;
        d1[n * NH1 + (lane >> 3)] = pd;
    }
}

// ---- CSR build: degree count ----
__global__ __launch_bounds__(256) void k_count(
    const int* __restrict__ ei, int* __restrict__ deg)
{
    int e = blockIdx.x * blockDim.x + threadIdx.x;
    if (e >= N_EDGES) return;
    atomicAdd(&deg[ei[N_EDGES + e]], 1);
}

// ---- scan phase 1: per-block (256-wide) reduction of deg -> bsum ----
__global__ __launch_bounds__(SCAN_B) void k_red(
    const int* __restrict__ deg, int* __restrict__ bsum)
{
    int t = threadIdx.x, lane = t & 63, wv = t >> 6;
    int i = blockIdx.x * SCAN_B + t;
    int v = (i < N_NODES) ? deg[i] : 0;
    #pragma unroll
    for (int off = 32; off; off >>= 1) v += __shfl_xor(v, off);
    __shared__ int s[4];
    if (lane == 0) s[wv] = v;
    __syncthreads();
    if (t == 0) bsum[blockIdx.x] = s[0] + s[1] + s[2] + s[3];
}

// ---- scan phase 2: single small block scans the 391 block sums ----
__global__ __launch_bounds__(512) void k_scan_small(
    const int* __restrict__ bsum, int* __restrict__ boff,
    int* __restrict__ rowptr)
{
    __shared__ int s[512];
    int t = threadIdx.x;
    int v = (t < N_SBLK) ? bsum[t] : 0;
    s[t] = v;
    __syncthreads();
    for (int off = 1; off < 512; off <<= 1) {
        int u = (t >= off) ? s[t - off] : 0;
        __syncthreads();
        s[t] += u;
        __syncthreads();
    }
    if (t < N_SBLK) boff[t] = s[t] - v;          // exclusive
    if (t == 511) rowptr[N_NODES] = s[511];      // total == N_EDGES
}

// ---- scan phase 3: in-block exclusive scan + block offset -> rowptr ----
__global__ __launch_bounds__(SCAN_B) void k_apply(
    const int* __restrict__ deg, const int* __restrict__ boff,
    int* __restrict__ rowptr)
{
    int t = threadIdx.x, lane = t & 63, wv = t >> 6;
    int i = blockIdx.x * SCAN_B + t;
    int v = (i < N_NODES) ? deg[i] : 0;
    int inc = v;
    #pragma unroll
    for (int off = 1; off < 64; off <<= 1) {
        int u = __shfl_up(inc, off);
        if (lane >= off) inc += u;
    }
    __shared__ int ws_[4];
    if (lane == 63) ws_[wv] = inc;
    __syncthreads();
    int add = 0;
    for (int k = 0; k < wv; k++) add += ws_[k];
    if (i < N_NODES) rowptr[i] = inc - v + add + boff[blockIdx.x];
}

// ---- CSR build: fill src / edge-weight arrays (split for lean node loops) ----
__global__ __launch_bounds__(256) void k_fill(
    const int* __restrict__ ei, const float* __restrict__ ea,
    const int* __restrict__ rowptr, int* __restrict__ cur,
    int* __restrict__ srcA, float* __restrict__ wA)
{
    int e = blockIdx.x * blockDim.x + threadIdx.x;
    if (e >= N_EDGES) return;
    int s = ei[e], d = ei[N_EDGES + e];
    int pos = rowptr[d] + atomicAdd(&cur[d], 1);
    srcA[pos] = s;
    wA[pos] = ea[e];
}

// ---- K_logit1: wave per dst node, lane = eL*8 + hL. Precompute
//      p1[pos,h] = exp(lrelu(s1[src,h] + d1[dst,h] + w*ae1[h])) as fp16.
//      Iterations independent -> deep pipelining; s1/d1 are L2-resident. ----
__global__ __launch_bounds__(256) void k_logit1(
    const int* __restrict__ rowptr, const int* __restrict__ srcA,
    const float* __restrict__ wA,
    const float* __restrict__ s1, const float* __restrict__ d1,
    const float* __restrict__ ae1, half_t* __restrict__ p1)
{
    int w = (blockIdx.x * blockDim.x + threadIdx.x) >> 6;
    int lane = threadIdx.x & 63;
    if (w >= N_NODES) return;
    int hL = lane & 7, eL = lane >> 3;
    float d1L = d1[w * NH1 + hL];
    float aeL = ae1[hL];
    int jb = rowptr[w], je = rowptr[w + 1];
    for (int base = jb; base < je; base += 8) {
        int idx = base + eL;
        bool valid = idx < je;
        int src = srcA[valid ? idx : jb];
        float wgt = wA[valid ? idx : jb];
        float l = lrelu(s1[src * NH1 + hL] + d1L + wgt * aeL);
        if (valid) p1[(size_t)base * NH1 + lane] = (half_t)__expf(l);
    }
}

// ---- K_node1: wave per dst node, lane = hA*8+f. Lean aggregation loop:
//      stream srcA + p1 (sequential), 4 independent H1 gathers + 4 chains.
//      Then fused elu + GEMM2 + s2/d2 dots. ----
__global__ __launch_bounds__(256) void k_node1(
    const int* __restrict__ rowptr, const int* __restrict__ srcA,
    const half_t* __restrict__ p1, const ushort_t* __restrict__ H1,
    const float* __restrict__ W2, const float* __restrict__ as2,
    const float* __restrict__ ad2,
    ushort_t* __restrict__ H2, float* __restrict__ s2, float* __restrict__ d2)
{
    int w = (blockIdx.x * blockDim.x + threadIdx.x) >> 6;
    int lane = threadIdx.x & 63;
    if (w >= N_NODES) return;
    int hA = lane >> 3;
    int jb = rowptr[w], je = rowptr[w + 1];
    float den0 = 0.f, den1 = 0.f, den2_ = 0.f, den3 = 0.f;
    float acc0 = 0.f, acc1 = 0.f, acc2 = 0.f, acc3 = 0.f;
    int j = jb;
    for (; j + 3 < je; j += 4) {
        int s0 = srcA[j], s1_ = srcA[j + 1], s2_ = srcA[j + 2], s3 = srcA[j + 3];
        float p0 = (float)p1[(size_t)(j + 0) * NH1 + hA];
        float p1v = (float)p1[(size_t)(j + 1) * NH1 + hA];
        float p2v = (float)p1[(size_t)(j + 2) * NH1 + hA];
        float p3 = (float)p1[(size_t)(j + 3) * NH1 + hA];
        float h0 = bf2f(H1[(size_t)s0 * C1 + lane]);
        float h1 = bf2f(H1[(size_t)s1_ * C1 + lane]);
        float h2_ = bf2f(H1[(size_t)s2_ * C1 + lane]);
        float h3 = bf2f(H1[(size_t)s3 * C1 + lane]);
        den0 += p0; den1 += p1v; den2_ += p2v; den3 += p3;
        acc0 = fmaf(p0, h0, acc0);
        acc1 = fmaf(p1v, h1, acc1);
        acc2 = fmaf(p2v, h2_, acc2);
        acc3 = fmaf(p3, h3, acc3);
    }
    for (; j < je; ++j) {
        int s0 = srcA[j];
        float p0 = (float)p1[(size_t)j * NH1 + hA];
        den0 += p0;
        acc0 = fmaf(p0, bf2f(H1[(size_t)s0 * C1 + lane]), acc0);
    }
    float den = (den0 + den1) + (den2_ + den3);
    float acc = (acc0 + acc1) + (acc2 + acc3);
    float o = acc / (den + 1e-16f);
    float r = o > 0.f ? o : __expf(o) - 1.f;   // elu
    int c = lane < C2 ? lane : 0;
    float h2 = 0.f;
    #pragma unroll 8
    for (int k = 0; k < C1; ++k) {
        float rk = __shfl(r, k);
        h2 = fmaf(rk, W2[k * C2 + c], h2);
    }
    float ps = lane < C2 ? h2 * as2[c] : 0.f;
    float pd = lane < C2 ? h2 * ad2[c] : 0.f;
    #pragma unroll
    for (int off = 32; off; off >>= 1) {
        ps += __shfl_xor(ps, off);
        pd += __shfl_xor(pd, off);
    }
    if (lane < C2) H2[(size_t)w * C1 + lane] = f2bf(h2);  // stride 64 (padded)
    if (lane == 0) { s2[w] = ps; d2[w] = pd; }
}

// ---- K_logit2: wave per dst node, lane = edge offset. p2[pos] fp16. ----
__global__ __launch_bounds__(256) void k_logit2(
    const int* __restrict__ rowptr, const int* __restrict__ srcA,
    const float* __restrict__ wA,
    const float* __restrict__ s2, const float* __restrict__ d2,
    const float* __restrict__ ae2, half_t* __restrict__ p2)
{
    int w = (blockIdx.x * blockDim.x + threadIdx.x) >> 6;
    int lane = threadIdx.x & 63;
    if (w >= N_NODES) return;
    float d2v = d2[w];
    float aev = ae2[0];
    int jb = rowptr[w], je = rowptr[w + 1];
    for (int idx = jb + lane; idx < je; idx += 64) {
        float l = lrelu(s2[srcA[idx]] + d2v + wA[idx] * aev);
        p2[idx] = (half_t)__expf(l);
    }
}

// ---- K_node2: wave per dst node, lane = class. Lean loop: stream srcA+p2,
//      4 independent H2 gathers + 4 chains. Fused log_softmax. ----
__global__ __launch_bounds__(256) void k_node2(
    const int* __restrict__ rowptr, const int* __restrict__ srcA,
    const half_t* __restrict__ p2, const ushort_t* __restrict__ H2,
    float* __restrict__ out)
{
    int w = (blockIdx.x * blockDim.x + threadIdx.x) >> 6;
    int lane = threadIdx.x & 63;
    if (w >= N_NODES) return;
    int c = lane < C2 ? lane : 0;
    int jb = rowptr[w], je = rowptr[w + 1];
    float den0 = 0.f, den1 = 0.f, den2_ = 0.f, den3 = 0.f;
    float acc0 = 0.f, acc1 = 0.f, acc2 = 0.f, acc3 = 0.f;
    int j = jb;
    for (; j + 3 < je; j += 4) {
        int s0 = srcA[j], s1_ = srcA[j + 1], s2_ = srcA[j + 2], s3 = srcA[j + 3];
        float p0 = (float)p2[j], p1v = (float)p2[j + 1];
        float p2v = (float)p2[j + 2], p3 = (float)p2[j + 3];
        float h0 = bf2f(H2[(size_t)s0 * C1 + c]);
        float h1 = bf2f(H2[(size_t)s1_ * C1 + c]);
        float h2_ = bf2f(H2[(size_t)s2_ * C1 + c]);
        float h3 = bf2f(H2[(size_t)s3 * C1 + c]);
        den0 += p0; den1 += p1v; den2_ += p2v; den3 += p3;
        acc0 = fmaf(p0, h0, acc0);
        acc1 = fmaf(p1v, h1, acc1);
        acc2 = fmaf(p2v, h2_, acc2);
        acc3 = fmaf(p3, h3, acc3);
    }
    for (; j < je; ++j) {
        int s0 = srcA[j];
        float p0 = (float)p2[j];
        den0 += p0;
        acc0 = fmaf(p0, bf2f(H2[(size_t)s0 * C1 + c]), acc0);
    }
    float den = (den0 + den1) + (den2_ + den3);
    float acc = (acc0 + acc1) + (acc2 + acc3);
    float o = acc / (den + 1e-16f);
    float v = lane < C2 ? o : -INFINITY;
    float m = v;
    #pragma unroll
    for (int off = 32; off; off >>= 1) m = fmaxf(m, __shfl_xor(m, off));
    float p = lane < C2 ? __expf(v - m) : 0.f;
    #pragma unroll
    for (int off = 32; off; off >>= 1) p += __shfl_xor(p, off);
    float ls = __logf(p);
    if (lane < C2) out[(size_t)w * C2 + lane] = v - m - ls;
}

extern "C" void kernel_launch(void* const* d_in, const int* in_sizes, int n_in,
                              void* d_out, int out_size, void* d_ws, size_t ws_size,
                              hipStream_t stream)
{
    const float* x   = (const float*)d_in[0];
    const int*   ei  = (const int*)  d_in[1];
    const float* ea  = (const float*)d_in[2];
    const float* W1  = (const float*)d_in[3];
    const float* as1 = (const float*)d_in[4];
    const float* ad1 = (const float*)d_in[5];
    const float* ae1 = (const float*)d_in[6];
    const float* W2  = (const float*)d_in[7];
    const float* as2 = (const float*)d_in[8];
    const float* ad2 = (const float*)d_in[9];
    const float* ae2 = (const float*)d_in[10];
    float* out = (float*)d_out;

    // workspace layout (4-byte units), aliased to stay <= 72 MB.
    // NOTE: rowptr needs 100,001 ints — s2 starts at +17,700,008 (R5 bug:
    // rowptr[N_NODES] overlapped s2[0] -> garbage edge ranges -> OOB abort).
    float*    ws     = (float*)d_ws;
    ushort_t* H1     = (ushort_t*)ws;                 // [0, 3.2M)  6.4M bf16
    ushort_t* H2     = (ushort_t*)(ws + 3200000);     // [3.2M, 6.4M) stride-64 bf16
    int*      srcA   = (int*)(ws + 6400000);          // [6.4M, 8.0M)
    float*    wA     = ws + 8000000;                  // [8.0M, 9.6M)
    half_t*   p1     = (half_t*)(ws + 9600000);       // [9.6M, 16.0M) 12.8M fp16
    int*      deg    = (int*)(ws + 9600000);          //   alias (dead before p1 written)
    int*      cur    = (int*)(ws + 9700000);          //   alias
    int*      bsum   = (int*)(ws + 9800000);          //   alias (391)
    int*      boff   = (int*)(ws + 9801000);          //   alias (391)
    float*    s1     = ws + 16000000;                 // [16.0M, 16.8M)
    half_t*   p2     = (half_t*)(ws + 16000000);      //   alias (s1 dead after k_logit1)
    float*    d1     = ws + 16800000;                 // [16.8M, 17.6M)
    int*      rowptr = (int*)(ws + 17600000);         // 100,001 ints
    float*    s2     = ws + 17700008;                 // 100,000
    float*    d2     = ws + 17800008;                 // 100,000

    hipMemsetAsync(deg, 0, 100000 * 4, stream);
    hipMemsetAsync(cur, 0, 100000 * 4, stream);

    k_gemm1     <<<N_NODES / 4, 256, 0, stream>>>(x, W1, as1, ad1, H1, s1, d1);
    k_count     <<<(N_EDGES + 255) / 256, 256, 0, stream>>>(ei, deg);
    k_red       <<<N_SBLK, SCAN_B, 0, stream>>>(deg, bsum);
    k_scan_small<<<1, 512, 0, stream>>>(bsum, boff, rowptr);
    k_apply     <<<N_SBLK, SCAN_B, 0, stream>>>(deg, boff, rowptr);
    k_fill      <<<(N_EDGES + 255) / 256, 256, 0, stream>>>(ei, ea, rowptr, cur, srcA, wA);
    k_logit1    <<<(N_NODES + 3) / 4, 256, 0, stream>>>(rowptr, srcA, wA, s1, d1, ae1, p1);
    k_node1     <<<(N_NODES + 3) / 4, 256, 0, stream>>>(rowptr, srcA, p1, H1,
                                                        W2, as2, ad2, H2, s2, d2);
    k_logit2    <<<(N_NODES + 3) / 4, 256, 0, stream>>>(rowptr, srcA, wA, s2, d2, ae2, p2);
    k_node2     <<<(N_NODES + 3) / 4, 256, 0, stream>>>(rowptr, srcA, p2, H2, out);
}

// Round 8
// 556.261 us; speedup vs baseline: 1.1408x; 1.1408x over previous
//
#include <hip/hip_runtime.h>
#include <math.h>

#define N_NODES 100000
#define N_EDGES 1600000
#define IN_F    128
#define NH1     8
#define HID     8
#define C1      64   // NH1*HID
#define C2      40   // N_CLASSES
#define SCAN_B  256
#define N_SBLK  ((N_NODES + SCAN_B - 1) / SCAN_B)   // 391

typedef unsigned short ushort_t;
typedef unsigned int uint_t;
typedef _Float16 half_t;

__device__ __forceinline__ float lrelu(float x) { return x > 0.f ? x : 0.2f * x; }
__device__ __forceinline__ ushort_t f2bf(float f) {
    uint_t u = __float_as_uint(f);
    u = (u + 0x7FFFu + ((u >> 16) & 1u)) >> 16;   // round-to-nearest-even
    return (ushort_t)u;
}
__device__ __forceinline__ float bf2f(ushort_t s) {
    return __uint_as_float(((uint_t)s) << 16);
}

// ---- K1: H1(bf16) = x@W1 ; s1[n,h], d1[n,h] attention dots. 4 nodes/block ----
__global__ __launch_bounds__(256) void k_gemm1(
    const float* __restrict__ x, const float* __restrict__ W1,
    const float* __restrict__ as1, const float* __restrict__ ad1,
    ushort_t* __restrict__ H1, float* __restrict__ s1, float* __restrict__ d1)
{
    __shared__ float xs[4][IN_F];
    int wv = threadIdx.x >> 6, lane = threadIdx.x & 63;
    int n = blockIdx.x * 4 + wv;
    ((float2*)xs[wv])[lane] = ((const float2*)(x + (size_t)n * IN_F))[lane];
    __syncthreads();
    float acc = 0.f;
    #pragma unroll
    for (int k = 0; k < IN_F; k += 4) {
        float4 xk = *(const float4*)&xs[wv][k];
        acc = fmaf(xk.x, W1[(k + 0) * C1 + lane], acc);
        acc = fmaf(xk.y, W1[(k + 1) * C1 + lane], acc);
        acc = fmaf(xk.z, W1[(k + 2) * C1 + lane], acc);
        acc = fmaf(xk.w, W1[(k + 3) * C1 + lane], acc);
    }
    H1[(size_t)n * C1 + lane] = f2bf(acc);
    float ps = acc * as1[lane], pd = acc * ad1[lane];  // lane == h*8+f
    #pragma unroll
    for (int off = 4; off; off >>= 1) {
        ps += __shfl_xor(ps, off);
        pd += __shfl_xor(pd, off);
    }
    if ((lane & 7) == 0) {
        s1[n * NH1 + (lane >> 3)] = ps;
        d1[n * NH1 + (lane >> 3)] = pd;
    }
}

// ---- CSR build: degree count + per-edge rank (old value of the counter) ----
__global__ __launch_bounds__(256) void k_count(
    const int* __restrict__ ei, int* __restrict__ deg, int* __restrict__ rank)
{
    int e = blockIdx.x * blockDim.x + threadIdx.x;
    if (e >= N_EDGES) return;
    rank[e] = atomicAdd(&deg[ei[N_EDGES + e]], 1);
}

// ---- scan phase 1: per-block (256-wide) reduction of deg -> bsum ----
__global__ __launch_bounds__(SCAN_B) void k_red(
    const int* __restrict__ deg, int* __restrict__ bsum)
{
    int t = threadIdx.x, lane = t & 63, wv = t >> 6;
    int i = blockIdx.x * SCAN_B + t;
    int v = (i < N_NODES) ? deg[i] : 0;
    #pragma unroll
    for (int off = 32; off; off >>= 1) v += __shfl_xor(v, off);
    __shared__ int s[4];
    if (lane == 0) s[wv] = v;
    __syncthreads();
    if (t == 0) bsum[blockIdx.x] = s[0] + s[1] + s[2] + s[3];
}

// ---- scan phase 2: single small block scans the 391 block sums ----
__global__ __launch_bounds__(512) void k_scan_small(
    const int* __restrict__ bsum, int* __restrict__ boff,
    int* __restrict__ rowptr)
{
    __shared__ int s[512];
    int t = threadIdx.x;
    int v = (t < N_SBLK) ? bsum[t] : 0;
    s[t] = v;
    __syncthreads();
    for (int off = 1; off < 512; off <<= 1) {
        int u = (t >= off) ? s[t - off] : 0;
        __syncthreads();
        s[t] += u;
        __syncthreads();
    }
    if (t < N_SBLK) boff[t] = s[t] - v;          // exclusive
    if (t == 511) rowptr[N_NODES] = s[511];      // total == N_EDGES
}

// ---- scan phase 3: in-block exclusive scan + block offset -> rowptr ----
__global__ __launch_bounds__(SCAN_B) void k_apply(
    const int* __restrict__ deg, const int* __restrict__ boff,
    int* __restrict__ rowptr)
{
    int t = threadIdx.x, lane = t & 63, wv = t >> 6;
    int i = blockIdx.x * SCAN_B + t;
    int v = (i < N_NODES) ? deg[i] : 0;
    int inc = v;
    #pragma unroll
    for (int off = 1; off < 64; off <<= 1) {
        int u = __shfl_up(inc, off);
        if (lane >= off) inc += u;
    }
    __shared__ int ws_[4];
    if (lane == 63) ws_[wv] = inc;
    __syncthreads();
    int add = 0;
    for (int k = 0; k < wv; k++) add += ws_[k];
    if (i < N_NODES) rowptr[i] = inc - v + add + boff[blockIdx.x];
}

// ---- CSR build: fill packed (src, w) — NO atomics (pos from rank),
//      ONE 8-B scattered store per edge. ----
__global__ __launch_bounds__(256) void k_fill(
    const int* __restrict__ ei, const float* __restrict__ ea,
    const int* __restrict__ rowptr, const int* __restrict__ rank,
    int2* __restrict__ edges)
{
    int e = blockIdx.x * blockDim.x + threadIdx.x;
    if (e >= N_EDGES) return;
    int s = ei[e], d = ei[N_EDGES + e];
    int pos = rowptr[d] + rank[e];
    edges[pos] = make_int2(s, __float_as_int(ea[e]));
}

// ---- K_logit1: wave per dst node, lane = eL*8 + hL. Precompute
//      p1[pos,h] = exp(lrelu(s1[src,h] + d1[dst,h] + w*ae1[h])) as fp16. ----
__global__ __launch_bounds__(256) void k_logit1(
    const int* __restrict__ rowptr, const int2* __restrict__ edges,
    const float* __restrict__ s1, const float* __restrict__ d1,
    const float* __restrict__ ae1, half_t* __restrict__ p1)
{
    int w = (blockIdx.x * blockDim.x + threadIdx.x) >> 6;
    int lane = threadIdx.x & 63;
    if (w >= N_NODES) return;
    int hL = lane & 7, eL = lane >> 3;
    float d1L = d1[w * NH1 + hL];
    float aeL = ae1[hL];
    int jb = rowptr[w], je = rowptr[w + 1];
    for (int base = jb; base < je; base += 8) {
        int idx = base + eL;
        bool valid = idx < je;
        int2 ed = edges[valid ? idx : jb];
        float l = lrelu(s1[ed.x * NH1 + hL] + d1L + __int_as_float(ed.y) * aeL);
        if (valid) p1[(size_t)base * NH1 + lane] = (half_t)__expf(l);
    }
}

// ---- K_node1: wave per dst node, lane = hA*8+f. Lean aggregation loop:
//      stream edges + p1 (sequential), 4 independent H1 gathers + 4 chains.
//      Then fused elu + GEMM2 + s2/d2 dots. ----
__global__ __launch_bounds__(256) void k_node1(
    const int* __restrict__ rowptr, const int2* __restrict__ edges,
    const half_t* __restrict__ p1, const ushort_t* __restrict__ H1,
    const float* __restrict__ W2, const float* __restrict__ as2,
    const float* __restrict__ ad2,
    ushort_t* __restrict__ H2, float* __restrict__ s2, float* __restrict__ d2)
{
    int w = (blockIdx.x * blockDim.x + threadIdx.x) >> 6;
    int lane = threadIdx.x & 63;
    if (w >= N_NODES) return;
    int hA = lane >> 3;
    int jb = rowptr[w], je = rowptr[w + 1];
    float den0 = 0.f, den1 = 0.f, den2_ = 0.f, den3 = 0.f;
    float acc0 = 0.f, acc1 = 0.f, acc2 = 0.f, acc3 = 0.f;
    int j = jb;
    for (; j + 3 < je; j += 4) {
        int s0 = edges[j].x, s1_ = edges[j + 1].x;
        int s2_ = edges[j + 2].x, s3 = edges[j + 3].x;
        float p0 = (float)p1[(size_t)(j + 0) * NH1 + hA];
        float p1v = (float)p1[(size_t)(j + 1) * NH1 + hA];
        float p2v = (float)p1[(size_t)(j + 2) * NH1 + hA];
        float p3 = (float)p1[(size_t)(j + 3) * NH1 + hA];
        float h0 = bf2f(H1[(size_t)s0 * C1 + lane]);
        float h1 = bf2f(H1[(size_t)s1_ * C1 + lane]);
        float h2_ = bf2f(H1[(size_t)s2_ * C1 + lane]);
        float h3 = bf2f(H1[(size_t)s3 * C1 + lane]);
        den0 += p0; den1 += p1v; den2_ += p2v; den3 += p3;
        acc0 = fmaf(p0, h0, acc0);
        acc1 = fmaf(p1v, h1, acc1);
        acc2 = fmaf(p2v, h2_, acc2);
        acc3 = fmaf(p3, h3, acc3);
    }
    for (; j < je; ++j) {
        int s0 = edges[j].x;
        float p0 = (float)p1[(size_t)j * NH1 + hA];
        den0 += p0;
        acc0 = fmaf(p0, bf2f(H1[(size_t)s0 * C1 + lane]), acc0);
    }
    float den = (den0 + den1) + (den2_ + den3);
    float acc = (acc0 + acc1) + (acc2 + acc3);
    float o = acc / (den + 1e-16f);
    float r = o > 0.f ? o : __expf(o) - 1.f;   // elu
    int c = lane < C2 ? lane : 0;
    float h2 = 0.f;
    #pragma unroll 8
    for (int k = 0; k < C1; ++k) {
        float rk = __shfl(r, k);
        h2 = fmaf(rk, W2[k * C2 + c], h2);
    }
    float ps = lane < C2 ? h2 * as2[c] : 0.f;
    float pd = lane < C2 ? h2 * ad2[c] : 0.f;
    #pragma unroll
    for (int off = 32; off; off >>= 1) {
        ps += __shfl_xor(ps, off);
        pd += __shfl_xor(pd, off);
    }
    if (lane < C2) H2[(size_t)w * C1 + lane] = f2bf(h2);  // stride 64 (padded)
    if (lane == 0) { s2[w] = ps; d2[w] = pd; }
}

// ---- K_logit2: wave per dst node, lane = edge offset. p2[pos] fp16. ----
__global__ __launch_bounds__(256) void k_logit2(
    const int* __restrict__ rowptr, const int2* __restrict__ edges,
    const float* __restrict__ s2, const float* __restrict__ d2,
    const float* __restrict__ ae2, half_t* __restrict__ p2)
{
    int w = (blockIdx.x * blockDim.x + threadIdx.x) >> 6;
    int lane = threadIdx.x & 63;
    if (w >= N_NODES) return;
    float d2v = d2[w];
    float aev = ae2[0];
    int jb = rowptr[w], je = rowptr[w + 1];
    for (int idx = jb + lane; idx < je; idx += 64) {
        int2 ed = edges[idx];
        float l = lrelu(s2[ed.x] + d2v + __int_as_float(ed.y) * aev);
        p2[idx] = (half_t)__expf(l);
    }
}

// ---- K_node2: wave per dst node, lane = class. Lean loop: stream edges+p2,
//      4 independent H2 gathers + 4 chains. Fused log_softmax. ----
__global__ __launch_bounds__(256) void k_node2(
    const int* __restrict__ rowptr, const int2* __restrict__ edges,
    const half_t* __restrict__ p2, const ushort_t* __restrict__ H2,
    float* __restrict__ out)
{
    int w = (blockIdx.x * blockDim.x + threadIdx.x) >> 6;
    int lane = threadIdx.x & 63;
    if (w >= N_NODES) return;
    int c = lane < C2 ? lane : 0;
    int jb = rowptr[w], je = rowptr[w + 1];
    float den0 = 0.f, den1 = 0.f, den2_ = 0.f, den3 = 0.f;
    float acc0 = 0.f, acc1 = 0.f, acc2 = 0.f, acc3 = 0.f;
    int j = jb;
    for (; j + 3 < je; j += 4) {
        int s0 = edges[j].x, s1_ = edges[j + 1].x;
        int s2_ = edges[j + 2].x, s3 = edges[j + 3].x;
        float p0 = (float)p2[j], p1v = (float)p2[j + 1];
        float p2v = (float)p2[j + 2], p3 = (float)p2[j + 3];
        float h0 = bf2f(H2[(size_t)s0 * C1 + c]);
        float h1 = bf2f(H2[(size_t)s1_ * C1 + c]);
        float h2_ = bf2f(H2[(size_t)s2_ * C1 + c]);
        float h3 = bf2f(H2[(size_t)s3 * C1 + c]);
        den0 += p0; den1 += p1v; den2_ += p2v; den3 += p3;
        acc0 = fmaf(p0, h0, acc0);
        acc1 = fmaf(p1v, h1, acc1);
        acc2 = fmaf(p2v, h2_, acc2);
        acc3 = fmaf(p3, h3, acc3);
    }
    for (; j < je; ++j) {
        int s0 = edges[j].x;
        float p0 = (float)p2[j];
        den0 += p0;
        acc0 = fmaf(p0, bf2f(H2[(size_t)s0 * C1 + c]), acc0);
    }
    float den = (den0 + den1) + (den2_ + den3);
    float acc = (acc0 + acc1) + (acc2 + acc3);
    float o = acc / (den + 1e-16f);
    float v = lane < C2 ? o : -INFINITY;
    float m = v;
    #pragma unroll
    for (int off = 32; off; off >>= 1) m = fmaxf(m, __shfl_xor(m, off));
    float p = lane < C2 ? __expf(v - m) : 0.f;
    #pragma unroll
    for (int off = 32; off; off >>= 1) p += __shfl_xor(p, off);
    float ls = __logf(p);
    if (lane < C2) out[(size_t)w * C2 + lane] = v - m - ls;
}

extern "C" void kernel_launch(void* const* d_in, const int* in_sizes, int n_in,
                              void* d_out, int out_size, void* d_ws, size_t ws_size,
                              hipStream_t stream)
{
    const float* x   = (const float*)d_in[0];
    const int*   ei  = (const int*)  d_in[1];
    const float* ea  = (const float*)d_in[2];
    const float* W1  = (const float*)d_in[3];
    const float* as1 = (const float*)d_in[4];
    const float* ad1 = (const float*)d_in[5];
    const float* ae1 = (const float*)d_in[6];
    const float* W2  = (const float*)d_in[7];
    const float* as2 = (const float*)d_in[8];
    const float* ad2 = (const float*)d_in[9];
    const float* ae2 = (const float*)d_in[10];
    float* out = (float*)d_out;

    // workspace layout (4-byte units), aliased to stay <= 72 MB.
    // rowptr needs 100,001 ints — s2 starts 8 words later (R5 overlap bug).
    // deg/rank/bsum/boff alias p1 (all dead after k_fill; p1 written after).
    // p2 aliases s1 (s1 dead after k_logit1; p2 written by k_logit2).
    float*    ws     = (float*)d_ws;
    ushort_t* H1     = (ushort_t*)ws;                 // [0, 3.2M)  6.4M bf16
    ushort_t* H2     = (ushort_t*)(ws + 3200000);     // [3.2M, 6.4M) stride-64 bf16
    int2*     edges  = (int2*)(ws + 6400000);         // [6.4M, 9.6M) 1.6M int2
    half_t*   p1     = (half_t*)(ws + 9600000);       // [9.6M, 16.0M) 12.8M fp16
    int*      deg    = (int*)(ws + 9600000);          //   alias
    int*      rank   = (int*)(ws + 9700000);          //   alias (1.6M ints)
    int*      bsum   = (int*)(ws + 11300000);         //   alias (391)
    int*      boff   = (int*)(ws + 11301000);         //   alias (391)
    float*    s1     = ws + 16000000;                 // [16.0M, 16.8M)
    half_t*   p2     = (half_t*)(ws + 16000000);      //   alias
    float*    d1     = ws + 16800000;                 // [16.8M, 17.6M)
    int*      rowptr = (int*)(ws + 17600000);         // 100,001 ints
    float*    s2     = ws + 17700008;                 // 100,000
    float*    d2     = ws + 17800008;                 // 100,000

    hipMemsetAsync(deg, 0, 100000 * 4, stream);

    k_gemm1     <<<N_NODES / 4, 256, 0, stream>>>(x, W1, as1, ad1, H1, s1, d1);
    k_count     <<<(N_EDGES + 255) / 256, 256, 0, stream>>>(ei, deg, rank);
    k_red       <<<N_SBLK, SCAN_B, 0, stream>>>(deg, bsum);
    k_scan_small<<<1, 512, 0, stream>>>(bsum, boff, rowptr);
    k_apply     <<<N_SBLK, SCAN_B, 0, stream>>>(deg, boff, rowptr);
    k_fill      <<<(N_EDGES + 255) / 256, 256, 0, stream>>>(ei, ea, rowptr, rank, edges);
    k_logit1    <<<(N_NODES + 3) / 4, 256, 0, stream>>>(rowptr, edges, s1, d1, ae1, p1);
    k_node1     <<<(N_NODES + 3) / 4, 256, 0, stream>>>(rowptr, edges, p1, H1,
                                                        W2, as2, ad2, H2, s2, d2);
    k_logit2    <<<(N_NODES + 3) / 4, 256, 0, stream>>>(rowptr, edges, s2, d2, ae2, p2);
    k_node2     <<<(N_NODES + 3) / 4, 256, 0, stream>>>(rowptr, edges, p2, H2, out);
}